// Round 3
// baseline (128.566 us; speedup 1.0000x reference)
//
#include <hip/hip_runtime.h>
#include <math.h>

#define HH 256
#define WW 256
#define CC 8
#define KK 25
#define ND 9
#define NB 2

// 4B-aligned float4: lets clang emit a single unaligned global_load_dwordx4
// (gfx950 has unaligned-access-mode) instead of asserting 16B alignment.
typedef float float4a __attribute__((ext_vector_type(4), aligned(4)));
typedef float float4v __attribute__((ext_vector_type(4)));

__global__ __launch_bounds__(256) void cost_kernel(
    const float* __restrict__ fm,    // [B][C][K][H][W]
    const float* __restrict__ mask,  // [B][K][H][W]
    const float* __restrict__ wgt,   // [C][K]
    float* __restrict__ out)         // [B][C][ND][H][W]
{
#pragma clang fp contract(off)
    const int tid = threadIdx.x;
    const int j0   = (tid & 63) << 2;  // first of 4 columns (wave = one row)
    const int rsub = tid >> 6;         // row within block (0..3)
    int bi = blockIdx.x;
    const int i = ((bi & 63) << 2) + rsub;  // row
    bi >>= 6;
    const int c = bi & 7; bi >>= 3;
    const int b = bi;

    const float* fmb = fm + (size_t)(b * CC + c) * KK * (HH * WW);
    const float* mb  = mask + (size_t)b * KK * (HH * WW) + i * WW + j0;

    float acc[ND][4];
#pragma unroll
    for (int dd = 0; dd < ND; ++dd)
#pragma unroll
        for (int e = 0; e < 4; ++e) acc[dd][e] = 0.f;
    float msum[4] = {0.f, 0.f, 0.f, 0.f};

    // Strict numpy order per pixel: k sequential; p=f*m; t=p*w; acc+=t.
    for (int k = 0; k < KK; ++k) {
        const int du = k / 5 - 2;
        const int dv = k % 5 - 2;
        const float4v mk = *(const float4a*)(mb + (size_t)k * (HH * WW));
#pragma unroll
        for (int e = 0; e < 4; ++e) msum[e] = __fadd_rn(msum[e], mk[e]);
        const float wk = wgt[c * KK + k];
        const float* fpk = fmb + (size_t)k * (HH * WW);
#pragma unroll
        for (int dd = 0; dd < ND; ++dd) {
            const int d = dd - 4;
            const int y = i - du * d;
            if ((unsigned)y >= HH) continue;   // wave-uniform skip; exact (t would be +/-0)
            const float* fp = fpk + y * WW;    // SGPR row base
            const int x0 = j0 - dv * d;        // lane x start, in [-8, 263]
            float f[4];
            if (x0 >= 0 && x0 <= WW - 4) {     // fully in-bounds: 1 vector load
                const float4v v = *(const float4a*)(fp + x0);
#pragma unroll
                for (int e = 0; e < 4; ++e) f[e] = v[e];
            } else {                            // edge lanes only (<=4 of 64)
#pragma unroll
                for (int e = 0; e < 4; ++e) {
                    const int x = x0 + e;
                    f[e] = ((unsigned)x < WW) ? fp[x] : 0.f;
                }
            }
#pragma unroll
            for (int e = 0; e < 4; ++e) {
                const float p = __fmul_rn(f[e], mk[e]);
                const float t = __fmul_rn(p, wk);
                acc[dd][e] = __fadd_rn(acc[dd][e], t);
            }
        }
    }

    float mavg[4];
#pragma unroll
    for (int e = 0; e < 4; ++e) mavg[e] = __fdiv_rn(msum[e], 25.0f);

    float* ob = out + (size_t)(b * CC + c) * ND * (HH * WW) + i * WW + j0;
#pragma unroll
    for (int dd = 0; dd < ND; ++dd) {
        float4v o;
#pragma unroll
        for (int e = 0; e < 4; ++e)
            o[e] = floorf(__fdiv_rn(acc[dd][e], mavg[e]));
        *(float4a*)(ob + (size_t)dd * (HH * WW)) = o;
    }
}

extern "C" void kernel_launch(void* const* d_in, const int* in_sizes, int n_in,
                              void* d_out, int out_size, void* d_ws, size_t ws_size,
                              hipStream_t stream) {
    const float* fm   = (const float*)d_in[0];
    const float* mask = (const float*)d_in[1];
    const float* wgt  = (const float*)d_in[2];
    float* out = (float*)d_out;

    dim3 grid(NB * CC * (HH / 4));  // 1024 blocks: (b, c, row-group of 4)
    dim3 block(256);                // wave = one row, thread = 4 columns
    cost_kernel<<<grid, block, 0, stream>>>(fm, mask, wgt, out);
}